// Round 1
// baseline (272.672 us; speedup 1.0000x reference)
//
#include <hip/hip_runtime.h>
#include <hip/hip_bf16.h>
#include <stdint.h>

// ---------------------------------------------------------------------------
// Loss_29592324669863: three fused cosine-Gram losses on MI355X.
//  - normalize rows (fp32) -> bf16 in ws
//  - fused MFMA Gram kernels (never materialize S):
//      MODE 0: class  (4096x4096, exp clamp 1e10, num/den row sums)
//      MODE 1: cross  (8192x8192, no clamp,      num/den row sums)
//      MODE 2: hash   (4096x4096, boundary-aware hashing, full sum)
//  - finalize -> out[3]
// ---------------------------------------------------------------------------

typedef __attribute__((ext_vector_type(8))) short bf16x8;   // 8 bf16 = 4 VGPR
typedef __attribute__((ext_vector_type(4))) float f32x4;

__device__ inline void gload_lds16(const void* g, void* l) {
  // async global->LDS, 16B/lane; LDS dest = wave-uniform base + lane*16
  __builtin_amdgcn_global_load_lds(
      (__attribute__((address_space(1))) void*)g,
      (__attribute__((address_space(3))) void*)l, 16, 0, 0);
}

// round-to-nearest-even f32 -> bf16 bits (finite inputs)
__device__ inline unsigned short f2bf(float x) {
  unsigned int u = __builtin_bit_cast(unsigned int, x);
  u = (u + 0x7fffu + ((u >> 16) & 1u)) >> 16;
  return (unsigned short)u;
}

// ---------------------------------------------------------------------------
// Normalize: 20480 rows of D=256 fp32 -> bf16, row / max(||row||, 1e-8).
// One wave per row; float4 loads (16B/lane), full-wave shfl reduce.
// rows 0..4095 LE->An, 4096..12287 FZ->Fn, 12288..16383 SE->Sn, rest LM->Ln
// ---------------------------------------------------------------------------
__global__ __launch_bounds__(256) void norm_kernel(
    const float* __restrict__ LE, const float* __restrict__ FZ,
    const float* __restrict__ SE, const float* __restrict__ LM,
    unsigned short* __restrict__ An, unsigned short* __restrict__ Fn,
    unsigned short* __restrict__ Sn, unsigned short* __restrict__ Ln) {
  const int tid = threadIdx.x;
  const int wid = tid >> 6, lane = tid & 63;
  const int row = blockIdx.x * 4 + wid;

  const float* src;
  unsigned short* dst;
  int r;
  if (row < 4096)       { src = LE; dst = An; r = row; }
  else if (row < 12288) { src = FZ; dst = Fn; r = row - 4096; }
  else if (row < 16384) { src = SE; dst = Sn; r = row - 12288; }
  else                  { src = LM; dst = Ln; r = row - 16384; }

  const float4 v = *(const float4*)(src + (size_t)r * 256 + lane * 4);
  float ss = v.x * v.x + v.y * v.y + v.z * v.z + v.w * v.w;
#pragma unroll
  for (int m = 1; m < 64; m <<= 1) ss += __shfl_xor(ss, m);
  const float scale = 1.0f / fmaxf(sqrtf(ss), 1e-8f);

  ushort4 o;
  o.x = f2bf(v.x * scale);
  o.y = f2bf(v.y * scale);
  o.z = f2bf(v.z * scale);
  o.w = f2bf(v.w * scale);
  *(ushort4*)(dst + (size_t)r * 256 + lane * 4) = o;
}

// ---------------------------------------------------------------------------
// Fused Gram kernel.
// Block: 256 threads = 4 waves (2x2), tile 128x128, K=256 in 4 windows of 64.
// LDS tiles [128 rows][128 B]; granule(16B) XOR-swizzle: phys = logical^(row&7)
// applied on the GLOBAL source address (LDS write stays linear for
// global_load_lds) and on the ds_read_b128 fragment address -> conflict-free.
// ---------------------------------------------------------------------------
template <int MODE>
__global__ __launch_bounds__(256) void sim_kernel(
    const unsigned short* __restrict__ X,   // row-side bf16 [N][256]
    const unsigned short* __restrict__ Y,   // col-side bf16 [N][256]
    const int* __restrict__ labels, int lmask,
    const float* __restrict__ tp, const float* __restrict__ xip,
    float* __restrict__ numv, float* __restrict__ denv,
    float* __restrict__ hacc) {
  __shared__ __align__(16) char At[16384];
  __shared__ __align__(16) char Bt[16384];
  __shared__ int lrS[128], lcS[128];
  __shared__ float hred[4];

  const int tid = threadIdx.x;
  const int lane = tid & 63, wid = tid >> 6;
  const int wr = wid >> 1, wc = wid & 1;     // wave position in 2x2
  const int g = lane >> 4, c = lane & 15;
  const int rb = blockIdx.y, cb = blockIdx.x;

  if (tid < 128) lrS[tid] = labels[(rb * 128 + tid) & lmask];
  else           lcS[tid - 128] = labels[(cb * 128 + (tid - 128)) & lmask];

  f32x4 acc[4][4];
  const f32x4 zero = {0.f, 0.f, 0.f, 0.f};
#pragma unroll
  for (int m = 0; m < 4; ++m)
#pragma unroll
    for (int n = 0; n < 4; ++n) acc[m][n] = zero;

  const char* Xb = (const char*)X;
  const char* Yb = (const char*)Y;

  for (int kk = 0; kk < 4; ++kk) {          // K windows of 64 (128 B)
#pragma unroll
    for (int t = 0; t < 4; ++t) {           // 4 x 4KB per 16KB tile
      const int o = tid * 16 + t * 4096;    // linear LDS byte offset
      const int r = o >> 7;                 // tile row
      const int p = (o >> 4) & 7;           // physical 16B granule
      const int gl = p ^ (r & 7);           // logical granule at global src
      gload_lds16(Xb + (size_t)(rb * 128 + r) * 512 + kk * 128 + gl * 16,
                  At + wid * 1024 + t * 4096);
      gload_lds16(Yb + (size_t)(cb * 128 + r) * 512 + kk * 128 + gl * 16,
                  Bt + wid * 1024 + t * 4096);
    }
    __syncthreads();                        // drains vmcnt before barrier
#pragma unroll
    for (int ks = 0; ks < 2; ++ks) {        // two K=32 MFMA steps
      bf16x8 af[4], bg[4];
#pragma unroll
      for (int m = 0; m < 4; ++m) {
        const int ra = wr * 64 + m * 16 + c;
        const int pp = (ks * 4 + g) ^ (ra & 7);
        af[m] = *(const bf16x8*)(At + ra * 128 + pp * 16);
      }
#pragma unroll
      for (int n = 0; n < 4; ++n) {
        const int rn = wc * 64 + n * 16 + c;
        const int pp = (ks * 4 + g) ^ (rn & 7);
        bg[n] = *(const bf16x8*)(Bt + rn * 128 + pp * 16);
      }
#pragma unroll
      for (int m = 0; m < 4; ++m)
#pragma unroll
        for (int n = 0; n < 4; ++n)
          acc[m][n] = __builtin_amdgcn_mfma_f32_16x16x32_bf16(
              af[m], bg[n], acc[m][n], 0, 0, 0);
    }
    __syncthreads();
  }

  // ---- epilogue: C/D layout col = lane&15, row = (lane>>4)*4 + reg ----
  if (MODE < 2) {
    const float inv_t = 1.0f / tp[0];
#pragma unroll
    for (int m = 0; m < 4; ++m) {
      const int rowbase = wr * 64 + m * 16 + g * 4;
#pragma unroll
      for (int reg = 0; reg < 4; ++reg) {
        const int lrow = lrS[rowbase + reg];
        float pn = 0.f, pd = 0.f;
#pragma unroll
        for (int n = 0; n < 4; ++n) {
          const float s = acc[m][n][reg];
          float e = __expf(s * inv_t);
          if (MODE == 0) e = fminf(e, 1e10f);
          pd += e;
          if (lrow == lcS[wc * 64 + n * 16 + c]) pn += e;
        }
#pragma unroll
        for (int msk = 1; msk < 16; msk <<= 1) {
          pn += __shfl_xor(pn, msk);
          pd += __shfl_xor(pd, msk);
        }
        if (c == 0) {
          const int grow = rb * 128 + rowbase + reg;
          atomicAdd(&numv[grow], pn);
          atomicAdd(&denv[grow], pd);
        }
      }
    }
  } else {
    const float xi = xip[0];
    float part = 0.f;
#pragma unroll
    for (int m = 0; m < 4; ++m)
#pragma unroll
      for (int reg = 0; reg < 4; ++reg) {
        const int lrow = lrS[wr * 64 + m * 16 + g * 4 + reg];
#pragma unroll
        for (int n = 0; n < 4; ++n) {
          const float cs = acc[m][n][reg];
          const float Dm = (1.0f - cs) * 0.5f;
          const float a = fmaxf(xi - Dm, 0.0f);
          part += (lrow == lcS[wc * 64 + n * 16 + c]) ? Dm * Dm : a * a;
        }
      }
#pragma unroll
    for (int msk = 1; msk < 64; msk <<= 1) part += __shfl_xor(part, msk);
    if (lane == 0) hred[wid] = part;
    __syncthreads();
    if (tid == 0) atomicAdd(hacc, hred[0] + hred[1] + hred[2] + hred[3]);
  }
}

// ---------------------------------------------------------------------------
__global__ __launch_bounds__(256) void finalize_kernel(
    const float* __restrict__ numc, const float* __restrict__ denc,
    const float* __restrict__ numx, const float* __restrict__ denx,
    const float* __restrict__ hacc, float* __restrict__ out) {
  const int tid = threadIdx.x;
  float s1 = 0.f, s2 = 0.f;
  for (int i = tid; i < 4096; i += 256)
    s1 += -logf(numc[i] / fmaxf(denc[i], 1e-10f));
  for (int i = tid; i < 8192; i += 256)
    s2 += -logf(numx[i] / fmaxf(denx[i], 1e-10f));
#pragma unroll
  for (int m = 1; m < 64; m <<= 1) {
    s1 += __shfl_xor(s1, m);
    s2 += __shfl_xor(s2, m);
  }
  __shared__ float r1[4], r2[4];
  const int wid = tid >> 6;
  if ((tid & 63) == 0) { r1[wid] = s1; r2[wid] = s2; }
  __syncthreads();
  if (tid == 0) {
    out[0] = (r1[0] + r1[1] + r1[2] + r1[3]) / 4096.0f;
    out[1] = (r2[0] + r2[1] + r2[2] + r2[3]) / 8192.0f;
    out[2] = hacc[0] / (4096.0f * 4096.0f);
  }
}

// ---------------------------------------------------------------------------
extern "C" void kernel_launch(void* const* d_in, const int* in_sizes, int n_in,
                              void* d_out, int out_size, void* d_ws,
                              size_t ws_size, hipStream_t stream) {
  const float* LE = (const float*)d_in[0];   // label_encodings [4096,256]
  const float* FZ = (const float*)d_in[1];   // fusion_z [2,4096,256]
  const float* SE = (const float*)d_in[2];   // sample_embeddings [4096,256]
  const float* LM = (const float*)d_in[3];   // label_embeddings [4096,256]
  const int* labels = (const int*)d_in[4];   // [4096]
  const float* tp = (const float*)d_in[5];   // temperature
  const float* xip = (const float*)d_in[6];  // xi
  float* out = (float*)d_out;

  char* ws = (char*)d_ws;
  unsigned short* An = (unsigned short*)(ws);              // 2 MB
  unsigned short* Fn = (unsigned short*)(ws + 2097152);    // 4 MB
  unsigned short* Sn = (unsigned short*)(ws + 6291456);    // 2 MB
  unsigned short* Ln = (unsigned short*)(ws + 8388608);    // 2 MB
  float* numc = (float*)(ws + 10485760);                   // 4096
  float* denc = numc + 4096;                               // 4096
  float* numx = denc + 4096;                               // 8192
  float* denx = numx + 8192;                               // 8192
  float* hacc = denx + 8192;                               // 1

  hipMemsetAsync(numc, 0, (size_t)(4096 * 2 + 8192 * 2 + 1) * sizeof(float),
                 stream);

  norm_kernel<<<dim3(20480 / 4), dim3(256), 0, stream>>>(LE, FZ, SE, LM, An,
                                                         Fn, Sn, Ln);
  sim_kernel<0><<<dim3(32, 32), dim3(256), 0, stream>>>(
      An, An, labels, 4095, tp, xip, numc, denc, hacc);
  sim_kernel<1><<<dim3(64, 64), dim3(256), 0, stream>>>(
      Fn, Fn, labels, 4095, tp, xip, numx, denx, hacc);
  sim_kernel<2><<<dim3(32, 32), dim3(256), 0, stream>>>(
      Sn, Ln, labels, 4095, tp, xip, nullptr, nullptr, hacc);
  finalize_kernel<<<dim3(1), dim3(256), 0, stream>>>(numc, denc, numx, denx,
                                                     hacc, out);
}

// Round 2
// 195.871 us; speedup vs baseline: 1.3921x; 1.3921x over previous
//
#include <hip/hip_runtime.h>
#include <hip/hip_bf16.h>
#include <stdint.h>

// ---------------------------------------------------------------------------
// Loss_29592324669863, round 2.
//  norm -> bf16; ONE fused Gram kernel (class/cross symmetric-triangular +
//  hash), 256x256 tiles, 8 waves, LDS-combined partials; finalize.
// ---------------------------------------------------------------------------

typedef __attribute__((ext_vector_type(8))) short bf16x8;   // 8 bf16
typedef __attribute__((ext_vector_type(4))) float f32x4;

__device__ inline void gload_lds16(const void* g, void* l) {
  __builtin_amdgcn_global_load_lds(
      (__attribute__((address_space(1))) void*)g,
      (__attribute__((address_space(3))) void*)l, 16, 0, 0);
}

__device__ inline unsigned short f2bf(float x) {  // RNE f32->bf16
  unsigned int u = __builtin_bit_cast(unsigned int, x);
  u = (u + 0x7fffu + ((u >> 16) & 1u)) >> 16;
  return (unsigned short)u;
}

// ---------------------------------------------------------------------------
__global__ __launch_bounds__(256) void norm_kernel(
    const float* __restrict__ LE, const float* __restrict__ FZ,
    const float* __restrict__ SE, const float* __restrict__ LM,
    unsigned short* __restrict__ An, unsigned short* __restrict__ Fn,
    unsigned short* __restrict__ Sn, unsigned short* __restrict__ Ln) {
  const int tid = threadIdx.x;
  const int wid = tid >> 6, lane = tid & 63;
  const int row = blockIdx.x * 4 + wid;

  const float* src;
  unsigned short* dst;
  int r;
  if (row < 4096)       { src = LE; dst = An; r = row; }
  else if (row < 12288) { src = FZ; dst = Fn; r = row - 4096; }
  else if (row < 16384) { src = SE; dst = Sn; r = row - 12288; }
  else                  { src = LM; dst = Ln; r = row - 16384; }

  const float4 v = *(const float4*)(src + (size_t)r * 256 + lane * 4);
  float ss = v.x * v.x + v.y * v.y + v.z * v.z + v.w * v.w;
#pragma unroll
  for (int m = 1; m < 64; m <<= 1) ss += __shfl_xor(ss, m);
  const float scale = 1.0f / fmaxf(sqrtf(ss), 1e-8f);

  ushort4 o;
  o.x = f2bf(v.x * scale);
  o.y = f2bf(v.y * scale);
  o.z = f2bf(v.z * scale);
  o.w = f2bf(v.w * scale);
  *(ushort4*)(dst + (size_t)r * 256 + lane * 4) = o;
}

// ---------------------------------------------------------------------------
// triangular block decode: t in [0, nb*(nb+1)/2), row rb has (nb-rb) blocks
__device__ inline void tri_decode(int t, int nb, int& rb, int& cb) {
  int r = 0;
  while (t >= nb - r) { t -= nb - r; ++r; }
  rb = r;
  cb = r + t;
}

// ---------------------------------------------------------------------------
// Fused Gram kernel. 512 thr = 8 waves (2 wr x 4 wc); tile 256x256; BK=64.
// modes: 0 class (An@An^T, tri, clamp), 1 cross (Fn@Fn^T, tri), 2 hash.
// LDS granule swizzle (phys = logical ^ (row&7)) on global src + ds_read.
// ---------------------------------------------------------------------------
__global__ __launch_bounds__(512) void fused_sim(
    const unsigned short* __restrict__ An, const unsigned short* __restrict__ Fn,
    const unsigned short* __restrict__ Sn, const unsigned short* __restrict__ Ln,
    const int* __restrict__ labels,
    const float* __restrict__ tp, const float* __restrict__ xip,
    float* __restrict__ numc, float* __restrict__ denc,
    float* __restrict__ numx, float* __restrict__ denx,
    float* __restrict__ hacc) {
  __shared__ __align__(16) char At[32768];
  __shared__ __align__(16) char Bt[32768];

  // XCD-aware swizzle: 920 blocks = 8 * 115 (bijective)
  const int hw = blockIdx.x;
  const int bid = (hw & 7) * 115 + (hw >> 3);

  int mode, rb, cb;
  const unsigned short *X, *Y;
  float *nv = nullptr, *dv = nullptr;
  if (bid < 136) {
    mode = 0; tri_decode(bid, 16, rb, cb); X = An; Y = An; nv = numc; dv = denc;
  } else if (bid < 664) {
    mode = 1; tri_decode(bid - 136, 32, rb, cb); X = Fn; Y = Fn; nv = numx; dv = denx;
  } else {
    mode = 2; const int t = bid - 664; rb = t >> 4; cb = t & 15; X = Sn; Y = Ln;
  }

  const int tid = threadIdx.x;
  const int lane = tid & 63, wid = tid >> 6;
  const int wr = wid >> 2, wc = wid & 3;     // 2 x 4 wave grid
  const int g = lane >> 4, c = lane & 15;

  f32x4 acc[8][4];
  const f32x4 zero = {0.f, 0.f, 0.f, 0.f};
#pragma unroll
  for (int m = 0; m < 8; ++m)
#pragma unroll
    for (int n = 0; n < 4; ++n) acc[m][n] = zero;

  // staging geometry (per thread, kk-invariant)
  const int srow = tid >> 3;                         // base row within 64-chunk
  const int sgl = ((tid >> 1) & 7) ^ (srow & 7);     // swizzled source granule
  const char* xsrc = (const char*)X + ((size_t)rb * 256 + srow) * 512 + sgl * 16;
  const char* ysrc = (const char*)Y + ((size_t)cb * 256 + srow) * 512 + sgl * 16;
  char* ldsa = At + wid * 1024;
  char* ldsb = Bt + wid * 1024;

  // fragment geometry
  const int pxs = c & 7;
  const char* aBase = At + (wr * 128 + c) * 128;
  const char* bBase = Bt + (wc * 64 + c) * 128;

  for (int kk = 0; kk < 4; ++kk) {
#pragma unroll
    for (int t = 0; t < 4; ++t) {   // t*64 rows => +t*32KB in global
      gload_lds16(xsrc + (size_t)t * 32768 + kk * 128, ldsa + t * 8192);
      gload_lds16(ysrc + (size_t)t * 32768 + kk * 128, ldsb + t * 8192);
    }
    __syncthreads();
#pragma unroll
    for (int ks = 0; ks < 2; ++ks) {
      const int px = ((ks * 4 + g) ^ pxs) * 16;
      bf16x8 af[8], bg[4];
#pragma unroll
      for (int m = 0; m < 8; ++m) af[m] = *(const bf16x8*)(aBase + m * 2048 + px);
#pragma unroll
      for (int n = 0; n < 4; ++n) bg[n] = *(const bf16x8*)(bBase + n * 2048 + px);
#pragma unroll
      for (int m = 0; m < 8; ++m)
#pragma unroll
        for (int n = 0; n < 4; ++n)
          acc[m][n] = __builtin_amdgcn_mfma_f32_16x16x32_bf16(
              af[m], bg[n], acc[m][n], 0, 0, 0);
    }
    __syncthreads();
  }

  // ---- epilogue; C/D layout: col = c (lane&15), row = g*4 + reg ----
  if (mode < 2) {
    const float invt = 1.0f / tp[0];
    const bool docol = (rb != cb);   // off-diagonal: add transposed (col) sums
    int collab[4];
#pragma unroll
    for (int n = 0; n < 4; ++n)
      collab[n] = labels[(cb * 256 + wc * 64 + n * 16 + c) & 4095];

    // reuse At as float scratch: rowN[256], rowD[256], colN[256], colD[256]
    float* sc = (float*)At;
    sc[tid] = 0.f;
    sc[tid + 512] = 0.f;
    __syncthreads();
    float* rowN = sc, *rowD = sc + 256, *colN = sc + 512, *colD = sc + 768;

    float cn[4] = {0.f, 0.f, 0.f, 0.f}, cd[4] = {0.f, 0.f, 0.f, 0.f};
#pragma unroll
    for (int m = 0; m < 8; ++m) {
#pragma unroll
      for (int reg = 0; reg < 4; ++reg) {
        const int rloc = wr * 128 + m * 16 + g * 4 + reg;
        const int rlab = labels[(rb * 256 + rloc) & 4095];
        float pn = 0.f, pd = 0.f;
#pragma unroll
        for (int n = 0; n < 4; ++n) {
          float e = __expf(acc[m][n][reg] * invt);
          if (mode == 0) e = fminf(e, 1e10f);
          pd += e;
          const bool eq = (rlab == collab[n]);
          const float en = eq ? e : 0.f;
          pn += en;
          if (docol) { cd[n] += e; cn[n] += en; }
        }
#pragma unroll
        for (int msk = 1; msk < 16; msk <<= 1) {
          pn += __shfl_xor(pn, msk);
          pd += __shfl_xor(pd, msk);
        }
        if (c == 0) {
          atomicAdd(&rowN[rloc], pn);
          atomicAdd(&rowD[rloc], pd);
        }
      }
    }
    if (docol) {
#pragma unroll
      for (int n = 0; n < 4; ++n) {
        float a = cn[n], b = cd[n];
        a += __shfl_xor(a, 16); b += __shfl_xor(b, 16);
        a += __shfl_xor(a, 32); b += __shfl_xor(b, 32);
        if (g == 0) {
          const int cl = wc * 64 + n * 16 + c;
          atomicAdd(&colN[cl], a);
          atomicAdd(&colD[cl], b);
        }
      }
    }
    __syncthreads();
    if (tid < 256) {
      atomicAdd(&nv[rb * 256 + tid], rowN[tid]);
      atomicAdd(&dv[rb * 256 + tid], rowD[tid]);
    } else if (docol) {
      atomicAdd(&nv[cb * 256 + (tid - 256)], colN[tid - 256]);
      atomicAdd(&dv[cb * 256 + (tid - 256)], colD[tid - 256]);
    }
  } else {
    const float xi = xip[0];
    int collab[4];
#pragma unroll
    for (int n = 0; n < 4; ++n)
      collab[n] = labels[(cb * 256 + wc * 64 + n * 16 + c) & 4095];
    float part = 0.f;
#pragma unroll
    for (int m = 0; m < 8; ++m)
#pragma unroll
      for (int reg = 0; reg < 4; ++reg) {
        const int rlab = labels[(rb * 256 + wr * 128 + m * 16 + g * 4 + reg) & 4095];
#pragma unroll
        for (int n = 0; n < 4; ++n) {
          const float cs = acc[m][n][reg];
          const float Dm = (1.0f - cs) * 0.5f;
          const float u = fmaxf(xi - Dm, 0.0f);
          part += (rlab == collab[n]) ? Dm * Dm : u * u;
        }
      }
#pragma unroll
    for (int msk = 1; msk < 64; msk <<= 1) part += __shfl_xor(part, msk);
    float* hp = (float*)At;
    if (lane == 0) hp[wid] = part;
    __syncthreads();
    if (tid == 0) {
      float s = 0.f;
#pragma unroll
      for (int w = 0; w < 8; ++w) s += hp[w];
      atomicAdd(hacc, s);
    }
  }
}

// ---------------------------------------------------------------------------
__global__ __launch_bounds__(256) void finalize_kernel(
    const float* __restrict__ numc, const float* __restrict__ denc,
    const float* __restrict__ numx, const float* __restrict__ denx,
    const float* __restrict__ hacc, float* __restrict__ out) {
  const int tid = threadIdx.x;
  float s1 = 0.f, s2 = 0.f;
  for (int i = tid; i < 4096; i += 256)
    s1 += -logf(numc[i] / fmaxf(denc[i], 1e-10f));
  for (int i = tid; i < 8192; i += 256)
    s2 += -logf(numx[i] / fmaxf(denx[i], 1e-10f));
#pragma unroll
  for (int m = 1; m < 64; m <<= 1) {
    s1 += __shfl_xor(s1, m);
    s2 += __shfl_xor(s2, m);
  }
  __shared__ float r1[4], r2[4];
  const int wid = tid >> 6;
  if ((tid & 63) == 0) { r1[wid] = s1; r2[wid] = s2; }
  __syncthreads();
  if (tid == 0) {
    out[0] = (r1[0] + r1[1] + r1[2] + r1[3]) / 4096.0f;
    out[1] = (r2[0] + r2[1] + r2[2] + r2[3]) / 8192.0f;
    out[2] = hacc[0] / (4096.0f * 4096.0f);
  }
}

// ---------------------------------------------------------------------------
extern "C" void kernel_launch(void* const* d_in, const int* in_sizes, int n_in,
                              void* d_out, int out_size, void* d_ws,
                              size_t ws_size, hipStream_t stream) {
  const float* LE = (const float*)d_in[0];
  const float* FZ = (const float*)d_in[1];
  const float* SE = (const float*)d_in[2];
  const float* LM = (const float*)d_in[3];
  const int* labels = (const int*)d_in[4];
  const float* tp = (const float*)d_in[5];
  const float* xip = (const float*)d_in[6];
  float* out = (float*)d_out;

  char* ws = (char*)d_ws;
  unsigned short* An = (unsigned short*)(ws);              // 2 MB
  unsigned short* Fn = (unsigned short*)(ws + 2097152);    // 4 MB
  unsigned short* Sn = (unsigned short*)(ws + 6291456);    // 2 MB
  unsigned short* Ln = (unsigned short*)(ws + 8388608);    // 2 MB
  float* numc = (float*)(ws + 10485760);                   // 4096
  float* denc = numc + 4096;                               // 4096
  float* numx = denc + 4096;                               // 8192
  float* denx = numx + 8192;                               // 8192
  float* hacc = denx + 8192;                               // 1

  hipMemsetAsync(numc, 0, (size_t)(4096 * 2 + 8192 * 2 + 1) * sizeof(float),
                 stream);

  norm_kernel<<<dim3(20480 / 4), dim3(256), 0, stream>>>(LE, FZ, SE, LM, An,
                                                         Fn, Sn, Ln);
  // 136 class (tri 16) + 528 cross (tri 32) + 256 hash = 920 blocks
  fused_sim<<<dim3(920), dim3(512), 0, stream>>>(An, Fn, Sn, Ln, labels, tp,
                                                 xip, numc, denc, numx, denx,
                                                 hacc);
  finalize_kernel<<<dim3(1), dim3(256), 0, stream>>>(numc, denc, numx, denx,
                                                     hacc, out);
}

// Round 3
// 175.757 us; speedup vs baseline: 1.5514x; 1.1144x over previous
//
#include <hip/hip_runtime.h>
#include <hip/hip_bf16.h>
#include <stdint.h>

// ---------------------------------------------------------------------------
// Loss_29592324669863, round 3.
//  - norm rows -> bf16 (+ folded zero-init of accumulators)
//  - ONE fused Gram kernel, m97-proven shape: 128x128 tile, 4 waves, BK=64,
//    single-buffer, correct granule swizzle, launch_bounds(256,3) -> 3 blk/CU.
//    class/cross use triangular symmetry (row+col sums per off-diag block).
//  - finalize: 3 blocks (one per loss).
// ---------------------------------------------------------------------------

typedef __attribute__((ext_vector_type(8))) short bf16x8;   // 8 bf16 = 4 VGPR
typedef __attribute__((ext_vector_type(4))) float f32x4;

__device__ inline void gload_lds16(const void* g, void* l) {
  __builtin_amdgcn_global_load_lds(
      (__attribute__((address_space(1))) void*)g,
      (__attribute__((address_space(3))) void*)l, 16, 0, 0);
}

__device__ inline unsigned short f2bf(float x) {  // RNE f32->bf16
  unsigned int u = __builtin_bit_cast(unsigned int, x);
  u = (u + 0x7fffu + ((u >> 16) & 1u)) >> 16;
  return (unsigned short)u;
}

// ---------------------------------------------------------------------------
__global__ __launch_bounds__(256) void norm_kernel(
    const float* __restrict__ LE, const float* __restrict__ FZ,
    const float* __restrict__ SE, const float* __restrict__ LM,
    unsigned short* __restrict__ An, unsigned short* __restrict__ Fn,
    unsigned short* __restrict__ Sn, unsigned short* __restrict__ Ln,
    float* __restrict__ zbuf) {
  const int tid = threadIdx.x;
  // folded zero-init of numc/denc/numx/denx/hacc (24577 floats)
  const int zidx = blockIdx.x * 256 + tid;
  if (zidx < 24577) zbuf[zidx] = 0.f;

  const int wid = tid >> 6, lane = tid & 63;
  const int row = blockIdx.x * 4 + wid;

  const float* src;
  unsigned short* dst;
  int r;
  if (row < 4096)       { src = LE; dst = An; r = row; }
  else if (row < 12288) { src = FZ; dst = Fn; r = row - 4096; }
  else if (row < 16384) { src = SE; dst = Sn; r = row - 12288; }
  else                  { src = LM; dst = Ln; r = row - 16384; }

  const float4 v = *(const float4*)(src + (size_t)r * 256 + lane * 4);
  float ss = v.x * v.x + v.y * v.y + v.z * v.z + v.w * v.w;
#pragma unroll
  for (int m = 1; m < 64; m <<= 1) ss += __shfl_xor(ss, m);
  const float scale = 1.0f / fmaxf(sqrtf(ss), 1e-8f);

  ushort4 o;
  o.x = f2bf(v.x * scale);
  o.y = f2bf(v.y * scale);
  o.z = f2bf(v.z * scale);
  o.w = f2bf(v.w * scale);
  *(ushort4*)(dst + (size_t)r * 256 + lane * 4) = o;
}

// ---------------------------------------------------------------------------
__device__ inline void tri_decode(int t, int nb, int& rb, int& cb) {
  int r = 0;
  while (t >= nb - r) { t -= nb - r; ++r; }
  rb = r;
  cb = r + t;
}

// ---------------------------------------------------------------------------
// Fused Gram kernel, 128x128 tile, 256 thr = 4 waves (2x2), BK=64 x 4.
// Granule swizzle (verified round 1): LDS phys granule (tid&7) holds logical
// (tid&7)^(row&7); ds_read applies the same XOR -> conflict-free b128 reads.
// ---------------------------------------------------------------------------
__global__ __launch_bounds__(256, 3) void fused_sim(
    const unsigned short* __restrict__ An, const unsigned short* __restrict__ Fn,
    const unsigned short* __restrict__ Sn, const unsigned short* __restrict__ Ln,
    const int* __restrict__ labels,
    const float* __restrict__ tp, const float* __restrict__ xip,
    float* __restrict__ numc, float* __restrict__ denc,
    float* __restrict__ numx, float* __restrict__ denx,
    float* __restrict__ hacc) {
  __shared__ __align__(16) char At[16384];
  __shared__ __align__(16) char Bt[16384];
  __shared__ int lrS[128], lcS[128];

  // XCD swizzle: 3632 = 8 * 454 (bijective)
  const int hw = blockIdx.x;
  const int bid = (hw & 7) * 454 + (hw >> 3);

  int mode, rb, cb;
  const unsigned short *X, *Y;
  float *nv = nullptr, *dv = nullptr;
  if (bid < 528) {            // class: tri over 32x32 blocks
    mode = 0; tri_decode(bid, 32, rb, cb); X = An; Y = An; nv = numc; dv = denc;
  } else if (bid < 2608) {    // cross: tri over 64x64 blocks
    mode = 1; tri_decode(bid - 528, 64, rb, cb); X = Fn; Y = Fn;
    nv = numx; dv = denx;
  } else {                    // hash: full 32x32 blocks
    mode = 2; const int t = bid - 2608; rb = t >> 5; cb = t & 31;
    X = Sn; Y = Ln;
  }

  const int tid = threadIdx.x;
  const int lane = tid & 63, wid = tid >> 6;
  const int wr = wid >> 1, wc = wid & 1;       // 2x2 wave grid
  const int g = lane >> 4, c = lane & 15;

  if (tid < 128) lrS[tid] = labels[(rb * 128 + tid) & 4095];
  else           lcS[tid - 128] = labels[(cb * 128 + (tid - 128)) & 4095];

  f32x4 acc[4][4];
  const f32x4 zero = {0.f, 0.f, 0.f, 0.f};
#pragma unroll
  for (int m = 0; m < 4; ++m)
#pragma unroll
    for (int n = 0; n < 4; ++n) acc[m][n] = zero;

  // staging geometry: 256 thr x 16B = 4KB per t-step (32 rows), 4 steps/kk
  const int srow = tid >> 3;                       // 0..31
  const int sgl = (tid & 7) ^ (srow & 7);          // CORRECT swizzle (r1 form)
  const char* xsrc =
      (const char*)X + ((size_t)rb * 128 + srow) * 512 + sgl * 16;
  const char* ysrc =
      (const char*)Y + ((size_t)cb * 128 + srow) * 512 + sgl * 16;
  char* ldsa = At + wid * 1024;
  char* ldsb = Bt + wid * 1024;

  // fragment geometry
  const char* aBase = At + (wr * 64 + c) * 128;
  const char* bBase = Bt + (wc * 64 + c) * 128;
  const int pxs = c & 7;

  for (int kk = 0; kk < 4; ++kk) {
#pragma unroll
    for (int t = 0; t < 4; ++t) {   // +32 rows per t => +16KB global
      gload_lds16(xsrc + (size_t)t * 16384 + kk * 128, ldsa + t * 4096);
      gload_lds16(ysrc + (size_t)t * 16384 + kk * 128, ldsb + t * 4096);
    }
    __syncthreads();
#pragma unroll
    for (int ks = 0; ks < 2; ++ks) {
      const int px = ((ks * 4 + g) ^ pxs) * 16;
      bf16x8 af[4], bg[4];
#pragma unroll
      for (int m = 0; m < 4; ++m) af[m] = *(const bf16x8*)(aBase + m * 2048 + px);
#pragma unroll
      for (int n = 0; n < 4; ++n) bg[n] = *(const bf16x8*)(bBase + n * 2048 + px);
#pragma unroll
      for (int m = 0; m < 4; ++m)
#pragma unroll
        for (int n = 0; n < 4; ++n)
          acc[m][n] = __builtin_amdgcn_mfma_f32_16x16x32_bf16(
              af[m], bg[n], acc[m][n], 0, 0, 0);
    }
    __syncthreads();
  }

  // ---- epilogue; C/D layout: col = c, row = g*4 + reg (verified r1) ----
  if (mode < 2) {
    const float invt = 1.0f / tp[0];
    const bool docol = (rb != cb);
    int collab[4];
#pragma unroll
    for (int n = 0; n < 4; ++n) collab[n] = lcS[wc * 64 + n * 16 + c];

    // LDS scratch in At: rowN[256] rowD[256] colN[256] colD[256] (plain
    // stores, unique writer per slot -> no atomics, no init)
    float* sc = (float*)At;
    float* rowN = sc, *rowD = sc + 256, *colN = sc + 512, *colD = sc + 768;

    float cn[4] = {0.f, 0.f, 0.f, 0.f}, cd[4] = {0.f, 0.f, 0.f, 0.f};
    float rn[16], rd[16];
#pragma unroll
    for (int m = 0; m < 4; ++m) {
#pragma unroll
      for (int reg = 0; reg < 4; ++reg) {
        const int rloc = wr * 64 + m * 16 + g * 4 + reg;
        const int rlab = lrS[rloc];
        float pn = 0.f, pd = 0.f;
#pragma unroll
        for (int n = 0; n < 4; ++n) {
          float e = __expf(acc[m][n][reg] * invt);
          if (mode == 0) e = fminf(e, 1e10f);
          pd += e;
          const bool eq = (rlab == collab[n]);
          const float en = eq ? e : 0.f;
          pn += en;
          cd[n] += e;
          cn[n] += en;
        }
#pragma unroll
        for (int msk = 1; msk < 16; msk <<= 1) {
          pn += __shfl_xor(pn, msk);
          pd += __shfl_xor(pd, msk);
        }
        rn[m * 4 + reg] = pn;
        rd[m * 4 + reg] = pd;
      }
    }
    __syncthreads();   // done reading At as bf16 tile (already true) + reuse
#pragma unroll
    for (int m = 0; m < 4; ++m)
#pragma unroll
      for (int reg = 0; reg < 4; ++reg) {
        const int rloc = wr * 64 + m * 16 + g * 4 + reg;
        if (c == 0) {
          rowN[wc * 128 + rloc] = rn[m * 4 + reg];
          rowD[wc * 128 + rloc] = rd[m * 4 + reg];
        }
      }
#pragma unroll
    for (int n = 0; n < 4; ++n) {
      float a = cn[n], b = cd[n];
      a += __shfl_xor(a, 16); b += __shfl_xor(b, 16);
      a += __shfl_xor(a, 32); b += __shfl_xor(b, 32);
      if (g == 0) {
        colN[wr * 128 + wc * 64 + n * 16 + c] = a;
        colD[wr * 128 + wc * 64 + n * 16 + c] = b;
      }
    }
    __syncthreads();
    if (tid < 128) {
      atomicAdd(&nv[rb * 128 + tid], rowN[tid] + rowN[128 + tid]);
      atomicAdd(&dv[rb * 128 + tid], rowD[tid] + rowD[128 + tid]);
    } else if (docol) {
      const int cl = tid - 128;
      atomicAdd(&nv[cb * 128 + cl], colN[cl] + colN[128 + cl]);
      atomicAdd(&dv[cb * 128 + cl], colD[cl] + colD[128 + cl]);
    }
  } else {
    const float xi = xip[0];
    int collab[4];
#pragma unroll
    for (int n = 0; n < 4; ++n) collab[n] = lcS[wc * 64 + n * 16 + c];
    float part = 0.f;
#pragma unroll
    for (int m = 0; m < 4; ++m)
#pragma unroll
      for (int reg = 0; reg < 4; ++reg) {
        const int rlab = lrS[wr * 64 + m * 16 + g * 4 + reg];
#pragma unroll
        for (int n = 0; n < 4; ++n) {
          const float cs = acc[m][n][reg];
          const float Dm = (1.0f - cs) * 0.5f;
          const float u = fmaxf(xi - Dm, 0.0f);
          part += (rlab == collab[n]) ? Dm * Dm : u * u;
        }
      }
#pragma unroll
    for (int msk = 1; msk < 64; msk <<= 1) part += __shfl_xor(part, msk);
    float* hp = (float*)At;
    __syncthreads();
    if (lane == 0) hp[wid] = part;
    __syncthreads();
    if (tid == 0) atomicAdd(hacc, hp[0] + hp[1] + hp[2] + hp[3]);
  }
}

// ---------------------------------------------------------------------------
__global__ __launch_bounds__(256) void finalize_kernel(
    const float* __restrict__ numc, const float* __restrict__ denc,
    const float* __restrict__ numx, const float* __restrict__ denx,
    const float* __restrict__ hacc, float* __restrict__ out) {
  const int tid = threadIdx.x;
  const int b = blockIdx.x;
  if (b == 2) {
    if (tid == 0) out[2] = hacc[0] / (4096.0f * 4096.0f);
    return;
  }
  const float* num = (b == 0) ? numc : numx;
  const float* den = (b == 0) ? denc : denx;
  const int n = (b == 0) ? 4096 : 8192;
  float s = 0.f;
  for (int i = tid; i < n; i += 256)
    s += -logf(num[i] / fmaxf(den[i], 1e-10f));
#pragma unroll
  for (int m = 1; m < 64; m <<= 1) s += __shfl_xor(s, m);
  __shared__ float r[4];
  if ((tid & 63) == 0) r[tid >> 6] = s;
  __syncthreads();
  if (tid == 0) out[b] = (r[0] + r[1] + r[2] + r[3]) / (float)n;
}

// ---------------------------------------------------------------------------
extern "C" void kernel_launch(void* const* d_in, const int* in_sizes, int n_in,
                              void* d_out, int out_size, void* d_ws,
                              size_t ws_size, hipStream_t stream) {
  const float* LE = (const float*)d_in[0];
  const float* FZ = (const float*)d_in[1];
  const float* SE = (const float*)d_in[2];
  const float* LM = (const float*)d_in[3];
  const int* labels = (const int*)d_in[4];
  const float* tp = (const float*)d_in[5];
  const float* xip = (const float*)d_in[6];
  float* out = (float*)d_out;

  char* ws = (char*)d_ws;
  unsigned short* An = (unsigned short*)(ws);              // 2 MB
  unsigned short* Fn = (unsigned short*)(ws + 2097152);    // 4 MB
  unsigned short* Sn = (unsigned short*)(ws + 6291456);    // 2 MB
  unsigned short* Ln = (unsigned short*)(ws + 8388608);    // 2 MB
  float* numc = (float*)(ws + 10485760);                   // 4096
  float* denc = numc + 4096;                               // 4096
  float* numx = denc + 4096;                               // 8192
  float* denx = numx + 8192;                               // 8192
  float* hacc = denx + 8192;                               // 1

  norm_kernel<<<dim3(5120), dim3(256), 0, stream>>>(LE, FZ, SE, LM, An, Fn,
                                                    Sn, Ln, numc);
  // 528 class (tri 32) + 2080 cross (tri 64) + 1024 hash = 3632 blocks
  fused_sim<<<dim3(3632), dim3(256), 0, stream>>>(An, Fn, Sn, Ln, labels, tp,
                                                  xip, numc, denc, numx, denx,
                                                  hacc);
  finalize_kernel<<<dim3(3), dim3(256), 0, stream>>>(numc, denc, numx, denx,
                                                     hacc, out);
}